// Round 11
// baseline (1103.112 us; speedup 1.0000x reference)
//
#include <hip/hip_runtime.h>
#include <math.h>

#define NN 4096
#define QQ 1024
#define LDA 1032              // padded leading dim
#define AF (1025 * 1032)      // floats in bordered matrix A

// ---------------- stats ----------------
__global__ void k_stats(const float* __restrict__ yt, const float* __restrict__ yp,
                        const int* __restrict__ idx, float* __restrict__ s,
                        int* __restrict__ c, float* __restrict__ scal) {
    int i = blockIdx.x * 256 + threadIdx.x;
    float r = yt[i] - yp[i];
    int q = idx[i];
    atomicAdd(&s[q], r);
    atomicAdd(&c[q], 1);
    float v = r * r;
    for (int o = 32; o > 0; o >>= 1) v += __shfl_down(v, o, 64);
    __shared__ float red[4];
    int lane = threadIdx.x & 63, wid = threadIdx.x >> 6;
    if (lane == 0) red[wid] = v;
    __syncthreads();
    if (threadIdx.x == 0) atomicAdd(&scal[0], red[0] + red[1] + red[2] + red[3]);
}

// ---------------- matvec ----------------
__global__ void k_matvec(const float* __restrict__ dist, const float* __restrict__ s,
                         const int* __restrict__ c, float* __restrict__ t,
                         float* __restrict__ w, float* __restrict__ sqc,
                         float* __restrict__ scal, const float* __restrict__ sbs) {
    int i = blockIdx.x;
    float sb0 = sbs[0];
    float inv2 = 1.0f / (2.0f * sbs[1]);
    const float* dr = dist + (size_t)i * QQ;
    float acc = 0.f;
    for (int j = threadIdx.x; j < QQ; j += 256)
        acc += __expf(-dr[j] * inv2) * s[j];
    for (int o = 32; o > 0; o >>= 1) acc += __shfl_down(acc, o, 64);
    __shared__ float red[4];
    int lane = threadIdx.x & 63, wid = threadIdx.x >> 6;
    if (lane == 0) red[wid] = acc;
    __syncthreads();
    if (threadIdx.x == 0) {
        float tot = (red[0] + red[1] + red[2] + red[3]) * sb0;
        t[i] = tot;
        float sq = sqrtf((float)c[i]);
        sqc[i] = sq;
        w[i] = sq * tot;
        atomicAdd(&scal[1], s[i] * tot);
    }
}

// ---------------- build bordered S ----------------
__global__ void k_build(const float* __restrict__ dist, const float* __restrict__ sqc,
                        const float* __restrict__ w, float* __restrict__ A,
                        const float* __restrict__ se_p, const float* __restrict__ sbs) {
    int i = blockIdx.x;  // 0..1024
    if (i == QQ) {
        for (int j = threadIdx.x; j < QQ; j += 256) A[(size_t)QQ * LDA + j] = w[j];
        return;
    }
    float sb0 = sbs[0];
    float inv2 = 1.0f / (2.0f * sbs[1]);
    float inv_se = 1.0f / se_p[0];
    float qi = sqc[i] * inv_se * sb0;
    const float* dr = dist + (size_t)i * QQ;
    float* ar = A + (size_t)i * LDA;
    for (int j = threadIdx.x; j < QQ; j += 256)
        ar[j] = ((i == j) ? 1.0f : 0.0f) + qi * sqc[j] * __expf(-dr[j] * inv2);
}

// ======== rank-2 register potrf of a 64x64 tile (256 threads) — proven ========
__device__ __forceinline__ void potrf64_run(float (&x)[16], int i, int q,
                                            float2 (&col2)[2][64]) {
#pragma unroll
    for (int qk = 0; qk < 4; ++qk) {
#pragma unroll
        for (int c2 = 0; c2 < 8; ++c2) {
            const int k = qk * 16 + 2 * c2;
            const int ck = 2 * c2;
            const int b = c2 & 1;
            if (q == qk) {
                float xk = x[ck];
                float d0 = __shfl(xk, k, 64);
                float rs0 = rsqrtf(d0);
                float l0 = (i == k) ? d0 * rs0 : xk * rs0;
                if (i >= k) x[ck] = l0;
                float lk1 = __shfl(l0, k + 1, 64);
                float x1v = fmaf(-l0, lk1, x[ck + 1]);
                float d1 = __shfl(x1v, k + 1, 64);
                float rs1 = rsqrtf(d1);
                float l1 = (i == k + 1) ? d1 * rs1 : x1v * rs1;
                if (i >= k + 1) x[ck + 1] = l1;
                col2[b][i] = make_float2(l0, l1);
            }
            __syncthreads();
            if (16 * q + 15 > k + 1 && i > k) {
                float2 lp = col2[b][i];
                const float4* cp = (const float4*)(&col2[b][16 * q]);
#pragma unroll
                for (int m2 = 0; m2 < 8; ++m2) {
                    float4 v = cp[m2];
                    if (16 * q + 2 * m2 > k + 1)
                        x[2 * m2] = fmaf(-lp.x, v.x, fmaf(-lp.y, v.y, x[2 * m2]));
                    if (16 * q + 2 * m2 + 1 > k + 1)
                        x[2 * m2 + 1] = fmaf(-lp.x, v.z, fmaf(-lp.y, v.w, x[2 * m2 + 1]));
                }
            }
        }
    }
}

// ======== template-unrolled trsm solve ========
template<int K, int M>
struct TAcc {
    static __device__ __forceinline__ void run(const float (&Lb)[64][65], const float (&x)[64],
                                               float& a0, float& a1) {
        if constexpr (M < K)     a0 = fmaf(-Lb[K][M], x[M], a0);
        if constexpr (M + 1 < K) a1 = fmaf(-Lb[K][M + 1], x[M + 1], a1);
        if constexpr (M + 2 < K) TAcc<K, M + 2>::run(Lb, x, a0, a1);
    }
};
template<int K>
struct TStep {
    static __device__ __forceinline__ void run(const float (&Lb)[64][65], const float (&dinv)[64],
                                               float (&x)[64]) {
        if constexpr (K < 64) {
            float a0 = x[K], a1 = 0.f;
            TAcc<K, 0>::run(Lb, x, a0, a1);
            x[K] = (a0 + a1) * dinv[K];
            TStep<K + 1>::run(Lb, dinv, x);
        }
    }
};

// ======== flag helpers ========
// R9 lesson: all-thread ACQUIRE polling = invalidate storm (~50us/hop).
// R10 lesson: relaxed plain loads can be served from the polling XCD's own
// (non-coherent) L2 — visibility becomes EVICTION-driven (~27us/hop).
// Fix: poll with an atomic RMW (fetch_add 0) — RMWs execute at the cross-XCD
// coherence point, never from a stale local copy. Release via atomic
// exchange for the same write-through guarantee. One acquire fence on trip.
__device__ __forceinline__ void st_rel(int* p, int v) {
    __hip_atomic_exchange(p, v, __ATOMIC_RELEASE, __HIP_MEMORY_SCOPE_AGENT);
}
__device__ __forceinline__ int poll_rmw(int* p) {
    return __hip_atomic_fetch_add(p, 0, __ATOMIC_RELAXED, __HIP_MEMORY_SCOPE_AGENT);
}
__device__ __forceinline__ void block_wait1(int* p, int v) {
    if (threadIdx.x == 0) {
        while (poll_rmw(p) < v) __builtin_amdgcn_s_sleep(1);
        __builtin_amdgcn_fence(__ATOMIC_ACQUIRE, "agent");
    }
    __syncthreads();
}
__device__ __forceinline__ void block_wait2(int* p1, int v1, int* p2, int v2) {
    if (threadIdx.x == 0) {
        while (poll_rmw(p1) < v1 || poll_rmw(p2) < v2) __builtin_amdgcn_s_sleep(1);
        __builtin_amdgcn_fence(__ATOMIC_ACQUIRE, "agent");
    }
    __syncthreads();
}
__device__ __forceinline__ void block_wait3(int* p1, int v1, int* p2, int v2,
                                            int* p3, int v3) {
    if (threadIdx.x == 0) {
        while (poll_rmw(p1) < v1 || poll_rmw(p2) < v2 || poll_rmw(p3) < v3)
            __builtin_amdgcn_s_sleep(1);
        __builtin_amdgcn_fence(__ATOMIC_ACQUIRE, "agent");
    }
    __syncthreads();
}

// ======== dataflow mega-kernel: whole blocked Cholesky + finalize ========
// Work items in topological order, popped via atomic counter (same as R9/R10):
//   idx 0              : POTRF0
//   per panel p=0..15  : TRSM(p,c) c=p+1..16 ; GEMM(p,i,j) j=p+1..15 asc, i=j..16
//                        (ONLY tile (p+1,p+1) fuses POTRF(p+1))
//   idx 937            : FINAL
__global__ __launch_bounds__(256, 2) void k_chol(float* __restrict__ A, int* __restrict__ cq,
                                                 const float* __restrict__ scal,
                                                 const float* __restrict__ se_p,
                                                 float* __restrict__ out) {
    __shared__ __align__(16) float ShA[64 * 68];
    __shared__ __align__(16) float ShB[64 * 68];
    __shared__ float2 col2[2][64];
    __shared__ int item[4];
    __shared__ float fred[2][4];
    int tid = threadIdx.x;
    int* qc = cq;
    int* pf = cq + 1;          // [16]
    int* td = cq + 17;         // [17][16]  c*16+p
    int* uc = cq + 17 + 272;   // [17][16]  i*16+j

    for (;;) {
        if (tid == 0) {
            int idx = atomicAdd(qc, 1);
            int ty = 4, pp = 0, ii = 0, jj = 0;
            if (idx == 0) ty = 0;
            else if (idx == 937) ty = 3;
            else if (idx < 937) {
                int r = idx - 1;
                for (int p = 0; p < 16; ++p) {
                    int n1 = 16 - p;
                    if (r < n1) { ty = 1; pp = p; ii = p + 1 + r; break; }
                    r -= n1;
                    int ng = (16 - p) * (17 - p) / 2 - 1;
                    if (r < ng) {
                        ty = 2; pp = p;
                        for (int j = p + 1; j <= 15; ++j) {
                            int cnt = 17 - j;
                            if (r < cnt) { jj = j; ii = j + r; break; }
                            r -= cnt;
                        }
                        break;
                    }
                    r -= ng;
                }
            }
            item[0] = ty; item[1] = pp; item[2] = ii; item[3] = jj;
        }
        __syncthreads();
        int ty = item[0], p = item[1], ci = item[2], cj = item[3];
        __syncthreads();
        if (ty == 4) return;

        if (ty == 0) {  // POTRF0
            int i = tid & 63, q = tid >> 6;
            float* row = A + (size_t)i * LDA + 16 * q;
            float x[16];
#pragma unroll
            for (int m4 = 0; m4 < 4; ++m4) {
                float4 v = ((const float4*)row)[m4];
                x[4 * m4] = v.x; x[4 * m4 + 1] = v.y; x[4 * m4 + 2] = v.z; x[4 * m4 + 3] = v.w;
            }
            potrf64_run(x, i, q, col2);
#pragma unroll
            for (int m4 = 0; m4 < 4; ++m4)
                ((float4*)row)[m4] = make_float4(x[4 * m4], x[4 * m4 + 1], x[4 * m4 + 2], x[4 * m4 + 3]);
            __syncthreads();
            if (tid == 0) st_rel(&pf[0], 1);

        } else if (ty == 1) {  // TRSM(p, chunk ci)
            block_wait2(&pf[p], 1, &uc[ci * 16 + p], p);
            float (*Lb)[65] = (float(*)[65])ShA;   // 64x65 fits in 64x68
            float* dinv = ShB;
            const float* db = A + (size_t)(p * 64) * LDA + p * 64;
            for (int idx2 = tid; idx2 < 4096; idx2 += 256) {
                int r = idx2 >> 6, cc = idx2 & 63;
                Lb[r][cc] = db[(size_t)r * LDA + cc];
            }
            __syncthreads();
            if (tid < 64) dinv[tid] = 1.0f / Lb[tid][tid];
            __syncthreads();
            if (tid < 64) {
                int r = ci * 64 + tid;
                if (r <= QQ) {
                    float* ar = A + (size_t)r * LDA + p * 64;
                    float x[64];
#pragma unroll
                    for (int jj4 = 0; jj4 < 16; ++jj4) {
                        float4 v = ((const float4*)ar)[jj4];
                        x[4 * jj4] = v.x; x[4 * jj4 + 1] = v.y; x[4 * jj4 + 2] = v.z; x[4 * jj4 + 3] = v.w;
                    }
                    TStep<0>::run(*(const float(*)[64][65])Lb, *(const float(*)[64])dinv, x);
#pragma unroll
                    for (int jj4 = 0; jj4 < 16; ++jj4)
                        ((float4*)ar)[jj4] = make_float4(x[4 * jj4], x[4 * jj4 + 1], x[4 * jj4 + 2], x[4 * jj4 + 3]);
                }
            }
            __syncthreads();
            if (tid == 0) st_rel(&td[ci * 16 + p], 1);

        } else if (ty == 2) {  // GEMM/SYRK(p, ci, cj); ONLY tile (p+1,p+1) fuses POTRF
            bool diag = (ci == cj);
            bool dfuse = diag && (cj == p + 1);
            if (diag) block_wait2(&td[ci * 16 + p], 1, &uc[ci * 16 + cj], p);
            else      block_wait3(&td[ci * 16 + p], 1, &td[cj * 16 + p], 1,
                                  &uc[ci * 16 + cj], p);
            int r0 = ci * 64, c0 = cj * 64, pc0 = p * 64;
            for (int idx2 = tid; idx2 < 1024; idx2 += 256) {
                int rr = idx2 >> 4, c4 = idx2 & 15;
                int gr = r0 + rr;
                float4 v = make_float4(0.f, 0.f, 0.f, 0.f);
                if (gr <= QQ) v = *(const float4*)(A + (size_t)gr * LDA + pc0 + 4 * c4);
                *(float4*)(ShA + rr * 68 + 4 * c4) = v;
                if (!diag) {
                    float4 u = *(const float4*)(A + (size_t)(c0 + rr) * LDA + pc0 + 4 * c4);
                    *(float4*)(ShB + rr * 68 + 4 * c4) = u;
                }
            }
            __syncthreads();
            const float* PB = diag ? ShA : ShB;
            int tx = tid & 15, ty2 = tid >> 4;
            float acc[4][4];
#pragma unroll
            for (int a = 0; a < 4; ++a)
#pragma unroll
                for (int b = 0; b < 4; ++b) acc[a][b] = 0.f;
            float4 arg[4], brg[4];
#pragma unroll 4
            for (int k4 = 0; k4 < 16; ++k4) {
#pragma unroll
                for (int a = 0; a < 4; ++a)
                    arg[a] = *(const float4*)(ShA + (ty2 + 16 * a) * 68 + 4 * k4);
#pragma unroll
                for (int b = 0; b < 4; ++b)
                    brg[b] = *(const float4*)(PB + (tx + 16 * b) * 68 + 4 * k4);
#pragma unroll
                for (int a = 0; a < 4; ++a)
#pragma unroll
                    for (int b = 0; b < 4; ++b) {
                        acc[a][b] = fmaf(arg[a].x, brg[b].x, acc[a][b]);
                        acc[a][b] = fmaf(arg[a].y, brg[b].y, acc[a][b]);
                        acc[a][b] = fmaf(arg[a].z, brg[b].z, acc[a][b]);
                        acc[a][b] = fmaf(arg[a].w, brg[b].w, acc[a][b]);
                    }
            }
            if (!dfuse) {
#pragma unroll
                for (int a = 0; a < 4; ++a) {
                    int rr = r0 + ty2 + 16 * a;
                    if (rr <= QQ) {
#pragma unroll
                        for (int b = 0; b < 4; ++b)
                            A[(size_t)rr * LDA + c0 + tx + 16 * b] -= acc[a][b];
                    }
                }
                __syncthreads();
                if (tid == 0) st_rel(&uc[ci * 16 + cj], p + 1);
            } else {
#pragma unroll
                for (int a = 0; a < 4; ++a) {
                    int lr = ty2 + 16 * a;
#pragma unroll
                    for (int b = 0; b < 4; ++b) {
                        int lc = tx + 16 * b;
                        float old = A[(size_t)(r0 + lr) * LDA + c0 + lc];
                        ShB[lr * 65 + lc] = old - acc[a][b];
                    }
                }
                __syncthreads();
                int i = tid & 63, q = tid >> 6;
                float x[16];
#pragma unroll
                for (int m = 0; m < 16; ++m) x[m] = ShB[i * 65 + 16 * q + m];
                potrf64_run(x, i, q, col2);
                float* row = A + (size_t)(r0 + i) * LDA + c0 + 16 * q;
#pragma unroll
                for (int m4 = 0; m4 < 4; ++m4)
                    ((float4*)row)[m4] = make_float4(x[4 * m4], x[4 * m4 + 1],
                                                     x[4 * m4 + 2], x[4 * m4 + 3]);
                __syncthreads();
                if (tid == 0) { st_rel(&uc[ci * 16 + cj], p + 1); st_rel(&pf[p + 1], 1); }
            }

        } else {  // FINAL
            block_wait2(&pf[15], 1, &td[16 * 16 + 15], 1);
            float v1 = 0.f, v2 = 0.f;
#pragma unroll
            for (int m = 0; m < 4; ++m) {
                int i = tid * 4 + m;
                v1 += 2.0f * __logf(A[(size_t)i * LDA + i]);
                float yv = A[(size_t)QQ * LDA + i];
                v2 += yv * yv;
            }
            for (int o = 32; o > 0; o >>= 1) {
                v1 += __shfl_down(v1, o, 64);
                v2 += __shfl_down(v2, o, 64);
            }
            int lane = tid & 63, wid = tid >> 6;
            if (lane == 0) { fred[0][wid] = v1; fred[1][wid] = v2; }
            __syncthreads();
            if (tid == 0) {
                float ld = fred[0][0] + fred[0][1] + fred[0][2] + fred[0][3];
                float yy = fred[1][0] + fred[1][1] + fred[1][2] + fred[1][3];
                float se = se_p[0], inv = 1.0f / se;
                float rr = scal[0], st = scal[1];
                float quad = rr * inv - inv * inv * (st - inv * yy);
                float logdetV = (float)NN * __logf(se) + ld;
                out[0] = 0.5f * (float)NN * 1.8378770664093453f + 0.5f * logdetV + 0.5f * quad;
            }
            __syncthreads();
        }
    }
}

extern "C" void kernel_launch(void* const* d_in, const int* in_sizes, int n_in,
                              void* d_out, int out_size, void* d_ws, size_t ws_size,
                              hipStream_t stream) {
    const float* yt   = (const float*)d_in[0];
    const float* yp   = (const float*)d_in[1];
    const int*   idx  = (const int*)d_in[2];
    const float* dist = (const float*)d_in[3];
    const float* se   = (const float*)d_in[4];
    const float* sbs  = (const float*)d_in[5];
    float* out = (float*)d_out;

    float* W    = (float*)d_ws;
    float* A    = W;                      // 1025 x LDA
    int*   c    = (int*)(W + AF);         // 1024 ints
    float* s    = W + AF + 1024;          // 1024
    float* scal = W + AF + 2048;          // 8 floats (rr, st, pad)
    int*   cq   = (int*)(W + AF + 2056);  // 1 + 16 + 272 + 272 = 561 ints
    float* t    = (float*)(cq + 561);     // 1024
    float* w    = t + 1024;               // 1024
    float* sqc  = w + 1024;               // 1024

    // zero c + s + scal + ctrl in one contiguous memset: (1024+1024+8+561)*4 B
    hipMemsetAsync(c, 0, (1024 + 1024 + 8 + 561) * sizeof(float), stream);

    k_stats<<<dim3(NN / 256), dim3(256), 0, stream>>>(yt, yp, idx, s, c, scal);
    k_matvec<<<dim3(QQ), dim3(256), 0, stream>>>(dist, s, c, t, w, sqc, scal, sbs);
    k_build<<<dim3(QQ + 1), dim3(256), 0, stream>>>(dist, sqc, w, A, se, sbs);
    k_chol<<<dim3(160), dim3(256), 0, stream>>>(A, cq, scal, se, out);
}

// Round 12
// 1091.740 us; speedup vs baseline: 1.0104x; 1.0104x over previous
//
#include <hip/hip_runtime.h>
#include <math.h>

#define NN 4096
#define QQ 1024
#define LDA 1032              // padded leading dim
#define AF (1025 * 1032)      // floats in bordered matrix A

// ---------------- stats ----------------
__global__ void k_stats(const float* __restrict__ yt, const float* __restrict__ yp,
                        const int* __restrict__ idx, float* __restrict__ s,
                        int* __restrict__ c, float* __restrict__ scal) {
    int i = blockIdx.x * 256 + threadIdx.x;
    float r = yt[i] - yp[i];
    int q = idx[i];
    atomicAdd(&s[q], r);
    atomicAdd(&c[q], 1);
    float v = r * r;
    for (int o = 32; o > 0; o >>= 1) v += __shfl_down(v, o, 64);
    __shared__ float red[4];
    int lane = threadIdx.x & 63, wid = threadIdx.x >> 6;
    if (lane == 0) red[wid] = v;
    __syncthreads();
    if (threadIdx.x == 0) atomicAdd(&scal[0], red[0] + red[1] + red[2] + red[3]);
}

// ---------------- matvec ----------------
__global__ void k_matvec(const float* __restrict__ dist, const float* __restrict__ s,
                         const int* __restrict__ c, float* __restrict__ t,
                         float* __restrict__ w, float* __restrict__ sqc,
                         float* __restrict__ scal, const float* __restrict__ sbs) {
    int i = blockIdx.x;
    float sb0 = sbs[0];
    float inv2 = 1.0f / (2.0f * sbs[1]);
    const float* dr = dist + (size_t)i * QQ;
    float acc = 0.f;
    for (int j = threadIdx.x; j < QQ; j += 256)
        acc += __expf(-dr[j] * inv2) * s[j];
    for (int o = 32; o > 0; o >>= 1) acc += __shfl_down(acc, o, 64);
    __shared__ float red[4];
    int lane = threadIdx.x & 63, wid = threadIdx.x >> 6;
    if (lane == 0) red[wid] = acc;
    __syncthreads();
    if (threadIdx.x == 0) {
        float tot = (red[0] + red[1] + red[2] + red[3]) * sb0;
        t[i] = tot;
        float sq = sqrtf((float)c[i]);
        sqc[i] = sq;
        w[i] = sq * tot;
        atomicAdd(&scal[1], s[i] * tot);
    }
}

// ---------------- build bordered S ----------------
__global__ void k_build(const float* __restrict__ dist, const float* __restrict__ sqc,
                        const float* __restrict__ w, float* __restrict__ A,
                        const float* __restrict__ se_p, const float* __restrict__ sbs) {
    int i = blockIdx.x;  // 0..1024
    if (i == QQ) {
        for (int j = threadIdx.x; j < QQ; j += 256) A[(size_t)QQ * LDA + j] = w[j];
        return;
    }
    float sb0 = sbs[0];
    float inv2 = 1.0f / (2.0f * sbs[1]);
    float inv_se = 1.0f / se_p[0];
    float qi = sqc[i] * inv_se * sb0;
    const float* dr = dist + (size_t)i * QQ;
    float* ar = A + (size_t)i * LDA;
    for (int j = threadIdx.x; j < QQ; j += 256)
        ar[j] = ((i == j) ? 1.0f : 0.0f) + qi * sqc[j] * __expf(-dr[j] * inv2);
}

// ======== rank-2 register potrf of a 64x64 tile (256 threads) — proven ========
__device__ __forceinline__ void potrf64_run(float (&x)[16], int i, int q,
                                            float2 (&col2)[2][64]) {
#pragma unroll
    for (int qk = 0; qk < 4; ++qk) {
#pragma unroll
        for (int c2 = 0; c2 < 8; ++c2) {
            const int k = qk * 16 + 2 * c2;
            const int ck = 2 * c2;
            const int b = c2 & 1;
            if (q == qk) {
                float xk = x[ck];
                float d0 = __shfl(xk, k, 64);
                float rs0 = rsqrtf(d0);
                float l0 = (i == k) ? d0 * rs0 : xk * rs0;
                if (i >= k) x[ck] = l0;
                float lk1 = __shfl(l0, k + 1, 64);
                float x1v = fmaf(-l0, lk1, x[ck + 1]);
                float d1 = __shfl(x1v, k + 1, 64);
                float rs1 = rsqrtf(d1);
                float l1 = (i == k + 1) ? d1 * rs1 : x1v * rs1;
                if (i >= k + 1) x[ck + 1] = l1;
                col2[b][i] = make_float2(l0, l1);
            }
            __syncthreads();
            if (16 * q + 15 > k + 1 && i > k) {
                float2 lp = col2[b][i];
                const float4* cp = (const float4*)(&col2[b][16 * q]);
#pragma unroll
                for (int m2 = 0; m2 < 8; ++m2) {
                    float4 v = cp[m2];
                    if (16 * q + 2 * m2 > k + 1)
                        x[2 * m2] = fmaf(-lp.x, v.x, fmaf(-lp.y, v.y, x[2 * m2]));
                    if (16 * q + 2 * m2 + 1 > k + 1)
                        x[2 * m2 + 1] = fmaf(-lp.x, v.z, fmaf(-lp.y, v.w, x[2 * m2 + 1]));
                }
            }
        }
    }
}

// ======== template-unrolled trsm solve ========
template<int K, int M>
struct TAcc {
    static __device__ __forceinline__ void run(const float (&Lb)[64][65], const float (&x)[64],
                                               float& a0, float& a1) {
        if constexpr (M < K)     a0 = fmaf(-Lb[K][M], x[M], a0);
        if constexpr (M + 1 < K) a1 = fmaf(-Lb[K][M + 1], x[M + 1], a1);
        if constexpr (M + 2 < K) TAcc<K, M + 2>::run(Lb, x, a0, a1);
    }
};
template<int K>
struct TStep {
    static __device__ __forceinline__ void run(const float (&Lb)[64][65], const float (&dinv)[64],
                                               float (&x)[64]) {
        if constexpr (K < 64) {
            float a0 = x[K], a1 = 0.f;
            TAcc<K, 0>::run(Lb, x, a0, a1);
            x[K] = (a0 + a1) * dinv[K];
            TStep<K + 1>::run(Lb, dinv, x);
        }
    }
};

// ======== flag helpers ========
// R9: all-thread ACQUIRE polls = invalidate storm. R10: relaxed loads = stale
// local L2, eviction-driven visibility. R11: RMW polls fresh BUT all flags
// shared ~3 cache lines (qc in the SAME line as pf[]) -> hundreds of RMWs
// serializing at the coherence point = ~30us queue delay. R12: every flag in
// its own 64B line + exponential backoff to cut poll pressure ~50x.
__device__ __forceinline__ void st_rel(int* p, int v) {
    __hip_atomic_exchange(p, v, __ATOMIC_RELEASE, __HIP_MEMORY_SCOPE_AGENT);
}
__device__ __forceinline__ int poll_rmw(int* p) {
    return __hip_atomic_fetch_add(p, 0, __ATOMIC_RELAXED, __HIP_MEMORY_SCOPE_AGENT);
}
__device__ __forceinline__ void backoff(int it) {
    if (it < 8)       __builtin_amdgcn_s_sleep(2);    // ~128 cyc
    else if (it < 32) __builtin_amdgcn_s_sleep(16);   // ~1k cyc
    else              __builtin_amdgcn_s_sleep(64);   // ~4k cyc (~1.7us)
}
__device__ __forceinline__ void block_wait1(int* p, int v) {
    if (threadIdx.x == 0) {
        int it = 0;
        while (poll_rmw(p) < v) backoff(it++);
        __builtin_amdgcn_fence(__ATOMIC_ACQUIRE, "agent");
    }
    __syncthreads();
}
__device__ __forceinline__ void block_wait2(int* p1, int v1, int* p2, int v2) {
    if (threadIdx.x == 0) {
        int it = 0;
        while (poll_rmw(p1) < v1 || poll_rmw(p2) < v2) backoff(it++);
        __builtin_amdgcn_fence(__ATOMIC_ACQUIRE, "agent");
    }
    __syncthreads();
}
__device__ __forceinline__ void block_wait3(int* p1, int v1, int* p2, int v2,
                                            int* p3, int v3) {
    if (threadIdx.x == 0) {
        int it = 0;
        while (poll_rmw(p1) < v1 || poll_rmw(p2) < v2 || poll_rmw(p3) < v3) backoff(it++);
        __builtin_amdgcn_fence(__ATOMIC_ACQUIRE, "agent");
    }
    __syncthreads();
}

// padded flag layout: every flag gets its own 64B line (16 ints)
#define PF(i)    (cq + 16 + 16 * (i))                        // 16 flags
#define TDF(c,p) (cq + 16 + 256 + 16 * ((c) * 16 + (p)))     // 17x16
#define UCF(i,j) (cq + 16 + 256 + 4352 + 16 * ((i) * 16 + (j)))  // 17x16
#define CTRL_INTS (16 + 256 + 4352 + 4352)                   // 8976

// ======== dataflow mega-kernel: whole blocked Cholesky + finalize ========
// Work items in topological order, popped via atomic counter (same as R9-R11):
//   idx 0              : POTRF0
//   per panel p=0..15  : TRSM(p,c) c=p+1..16 ; GEMM(p,i,j) j=p+1..15 asc, i=j..16
//                        (ONLY tile (p+1,p+1) fuses POTRF(p+1))
//   idx 937            : FINAL
__global__ __launch_bounds__(256, 2) void k_chol(float* __restrict__ A, int* __restrict__ cq,
                                                 const float* __restrict__ scal,
                                                 const float* __restrict__ se_p,
                                                 float* __restrict__ out) {
    __shared__ __align__(16) float ShA[64 * 68];
    __shared__ __align__(16) float ShB[64 * 68];
    __shared__ float2 col2[2][64];
    __shared__ int item[4];
    __shared__ float fred[2][4];
    int tid = threadIdx.x;

    for (;;) {
        if (tid == 0) {
            int idx = atomicAdd(cq, 1);   // cq line holds only the queue counter
            int ty = 4, pp = 0, ii = 0, jj = 0;
            if (idx == 0) ty = 0;
            else if (idx == 937) ty = 3;
            else if (idx < 937) {
                int r = idx - 1;
                for (int p = 0; p < 16; ++p) {
                    int n1 = 16 - p;
                    if (r < n1) { ty = 1; pp = p; ii = p + 1 + r; break; }
                    r -= n1;
                    int ng = (16 - p) * (17 - p) / 2 - 1;
                    if (r < ng) {
                        ty = 2; pp = p;
                        for (int j = p + 1; j <= 15; ++j) {
                            int cnt = 17 - j;
                            if (r < cnt) { jj = j; ii = j + r; break; }
                            r -= cnt;
                        }
                        break;
                    }
                    r -= ng;
                }
            }
            item[0] = ty; item[1] = pp; item[2] = ii; item[3] = jj;
        }
        __syncthreads();
        int ty = item[0], p = item[1], ci = item[2], cj = item[3];
        __syncthreads();
        if (ty == 4) return;

        if (ty == 0) {  // POTRF0
            int i = tid & 63, q = tid >> 6;
            float* row = A + (size_t)i * LDA + 16 * q;
            float x[16];
#pragma unroll
            for (int m4 = 0; m4 < 4; ++m4) {
                float4 v = ((const float4*)row)[m4];
                x[4 * m4] = v.x; x[4 * m4 + 1] = v.y; x[4 * m4 + 2] = v.z; x[4 * m4 + 3] = v.w;
            }
            potrf64_run(x, i, q, col2);
#pragma unroll
            for (int m4 = 0; m4 < 4; ++m4)
                ((float4*)row)[m4] = make_float4(x[4 * m4], x[4 * m4 + 1], x[4 * m4 + 2], x[4 * m4 + 3]);
            __syncthreads();
            if (tid == 0) st_rel(PF(0), 1);

        } else if (ty == 1) {  // TRSM(p, chunk ci)
            block_wait2(PF(p), 1, UCF(ci, p), p);
            float (*Lb)[65] = (float(*)[65])ShA;   // 64x65 fits in 64x68
            float* dinv = ShB;
            const float* db = A + (size_t)(p * 64) * LDA + p * 64;
            for (int idx2 = tid; idx2 < 4096; idx2 += 256) {
                int r = idx2 >> 6, cc = idx2 & 63;
                Lb[r][cc] = db[(size_t)r * LDA + cc];
            }
            __syncthreads();
            if (tid < 64) dinv[tid] = 1.0f / Lb[tid][tid];
            __syncthreads();
            if (tid < 64) {
                int r = ci * 64 + tid;
                if (r <= QQ) {
                    float* ar = A + (size_t)r * LDA + p * 64;
                    float x[64];
#pragma unroll
                    for (int jj4 = 0; jj4 < 16; ++jj4) {
                        float4 v = ((const float4*)ar)[jj4];
                        x[4 * jj4] = v.x; x[4 * jj4 + 1] = v.y; x[4 * jj4 + 2] = v.z; x[4 * jj4 + 3] = v.w;
                    }
                    TStep<0>::run(*(const float(*)[64][65])Lb, *(const float(*)[64])dinv, x);
#pragma unroll
                    for (int jj4 = 0; jj4 < 16; ++jj4)
                        ((float4*)ar)[jj4] = make_float4(x[4 * jj4], x[4 * jj4 + 1], x[4 * jj4 + 2], x[4 * jj4 + 3]);
                }
            }
            __syncthreads();
            if (tid == 0) st_rel(TDF(ci, p), 1);

        } else if (ty == 2) {  // GEMM/SYRK(p, ci, cj); ONLY tile (p+1,p+1) fuses POTRF
            bool diag = (ci == cj);
            bool dfuse = diag && (cj == p + 1);
            if (diag) block_wait2(TDF(ci, p), 1, UCF(ci, cj), p);
            else      block_wait3(TDF(ci, p), 1, TDF(cj, p), 1, UCF(ci, cj), p);
            int r0 = ci * 64, c0 = cj * 64, pc0 = p * 64;
            for (int idx2 = tid; idx2 < 1024; idx2 += 256) {
                int rr = idx2 >> 4, c4 = idx2 & 15;
                int gr = r0 + rr;
                float4 v = make_float4(0.f, 0.f, 0.f, 0.f);
                if (gr <= QQ) v = *(const float4*)(A + (size_t)gr * LDA + pc0 + 4 * c4);
                *(float4*)(ShA + rr * 68 + 4 * c4) = v;
                if (!diag) {
                    float4 u = *(const float4*)(A + (size_t)(c0 + rr) * LDA + pc0 + 4 * c4);
                    *(float4*)(ShB + rr * 68 + 4 * c4) = u;
                }
            }
            __syncthreads();
            const float* PB = diag ? ShA : ShB;
            int tx = tid & 15, ty2 = tid >> 4;
            float acc[4][4];
#pragma unroll
            for (int a = 0; a < 4; ++a)
#pragma unroll
                for (int b = 0; b < 4; ++b) acc[a][b] = 0.f;
            float4 arg[4], brg[4];
#pragma unroll 4
            for (int k4 = 0; k4 < 16; ++k4) {
#pragma unroll
                for (int a = 0; a < 4; ++a)
                    arg[a] = *(const float4*)(ShA + (ty2 + 16 * a) * 68 + 4 * k4);
#pragma unroll
                for (int b = 0; b < 4; ++b)
                    brg[b] = *(const float4*)(PB + (tx + 16 * b) * 68 + 4 * k4);
#pragma unroll
                for (int a = 0; a < 4; ++a)
#pragma unroll
                    for (int b = 0; b < 4; ++b) {
                        acc[a][b] = fmaf(arg[a].x, brg[b].x, acc[a][b]);
                        acc[a][b] = fmaf(arg[a].y, brg[b].y, acc[a][b]);
                        acc[a][b] = fmaf(arg[a].z, brg[b].z, acc[a][b]);
                        acc[a][b] = fmaf(arg[a].w, brg[b].w, acc[a][b]);
                    }
            }
            if (!dfuse) {
#pragma unroll
                for (int a = 0; a < 4; ++a) {
                    int rr = r0 + ty2 + 16 * a;
                    if (rr <= QQ) {
#pragma unroll
                        for (int b = 0; b < 4; ++b)
                            A[(size_t)rr * LDA + c0 + tx + 16 * b] -= acc[a][b];
                    }
                }
                __syncthreads();
                if (tid == 0) st_rel(UCF(ci, cj), p + 1);
            } else {
#pragma unroll
                for (int a = 0; a < 4; ++a) {
                    int lr = ty2 + 16 * a;
#pragma unroll
                    for (int b = 0; b < 4; ++b) {
                        int lc = tx + 16 * b;
                        float old = A[(size_t)(r0 + lr) * LDA + c0 + lc];
                        ShB[lr * 65 + lc] = old - acc[a][b];
                    }
                }
                __syncthreads();
                int i = tid & 63, q = tid >> 6;
                float x[16];
#pragma unroll
                for (int m = 0; m < 16; ++m) x[m] = ShB[i * 65 + 16 * q + m];
                potrf64_run(x, i, q, col2);
                float* row = A + (size_t)(r0 + i) * LDA + c0 + 16 * q;
#pragma unroll
                for (int m4 = 0; m4 < 4; ++m4)
                    ((float4*)row)[m4] = make_float4(x[4 * m4], x[4 * m4 + 1],
                                                     x[4 * m4 + 2], x[4 * m4 + 3]);
                __syncthreads();
                if (tid == 0) { st_rel(UCF(ci, cj), p + 1); st_rel(PF(p + 1), 1); }
            }

        } else {  // FINAL
            block_wait2(PF(15), 1, TDF(16, 15), 1);
            float v1 = 0.f, v2 = 0.f;
#pragma unroll
            for (int m = 0; m < 4; ++m) {
                int i = tid * 4 + m;
                v1 += 2.0f * __logf(A[(size_t)i * LDA + i]);
                float yv = A[(size_t)QQ * LDA + i];
                v2 += yv * yv;
            }
            for (int o = 32; o > 0; o >>= 1) {
                v1 += __shfl_down(v1, o, 64);
                v2 += __shfl_down(v2, o, 64);
            }
            int lane = tid & 63, wid = tid >> 6;
            if (lane == 0) { fred[0][wid] = v1; fred[1][wid] = v2; }
            __syncthreads();
            if (tid == 0) {
                float ld = fred[0][0] + fred[0][1] + fred[0][2] + fred[0][3];
                float yy = fred[1][0] + fred[1][1] + fred[1][2] + fred[1][3];
                float se = se_p[0], inv = 1.0f / se;
                float rr = scal[0], st = scal[1];
                float quad = rr * inv - inv * inv * (st - inv * yy);
                float logdetV = (float)NN * __logf(se) + ld;
                out[0] = 0.5f * (float)NN * 1.8378770664093453f + 0.5f * logdetV + 0.5f * quad;
            }
            __syncthreads();
        }
    }
}

extern "C" void kernel_launch(void* const* d_in, const int* in_sizes, int n_in,
                              void* d_out, int out_size, void* d_ws, size_t ws_size,
                              hipStream_t stream) {
    const float* yt   = (const float*)d_in[0];
    const float* yp   = (const float*)d_in[1];
    const int*   idx  = (const int*)d_in[2];
    const float* dist = (const float*)d_in[3];
    const float* se   = (const float*)d_in[4];
    const float* sbs  = (const float*)d_in[5];
    float* out = (float*)d_out;

    float* W    = (float*)d_ws;
    float* A    = W;                      // 1025 x LDA
    int*   c    = (int*)(W + AF);         // 1024 ints
    float* s    = W + AF + 1024;          // 1024
    float* scal = W + AF + 2048;          // 8 floats (rr, st, pad)
    int*   cq   = (int*)(W + AF + 2056);  // CTRL_INTS padded flags
    float* t    = (float*)(cq + CTRL_INTS);  // 1024
    float* w    = t + 1024;               // 1024
    float* sqc  = w + 1024;               // 1024

    // zero c + s + scal + control flags in one contiguous memset
    hipMemsetAsync(c, 0, (size_t)(1024 + 1024 + 8 + CTRL_INTS) * sizeof(int), stream);

    k_stats<<<dim3(NN / 256), dim3(256), 0, stream>>>(yt, yp, idx, s, c, scal);
    k_matvec<<<dim3(QQ), dim3(256), 0, stream>>>(dist, s, c, t, w, sqc, scal, sbs);
    k_build<<<dim3(QQ + 1), dim3(256), 0, stream>>>(dist, sqc, w, A, se, sbs);
    k_chol<<<dim3(160), dim3(256), 0, stream>>>(A, cq, scal, se, out);
}